// Round 8
// baseline (88.214 us; speedup 1.0000x reference)
//
#include <hip/hip_runtime.h>
#include <hip/hip_bf16.h>

// Problem constants
#define L_SEQ 2048
#define BATCH 2
#define ROWS 4096          // L*B, row index = l*2 + b
#define E 1024
#define NH 16
#define HD 64

typedef __attribute__((ext_vector_type(4))) float f32x4;
typedef __attribute__((ext_vector_type(8))) __bf16 bf16x8;

// XOR swizzle for 128-byte-row LDS tiles (break same-bank column reads)
#define SWZ(byt) ((byt) ^ ((((byt) >> 7) & 7) << 4))

__device__ __forceinline__ void gload16(const void* g, void* l) {
    __builtin_amdgcn_global_load_lds((const __attribute__((address_space(1))) void*)g,
                                     (__attribute__((address_space(3))) void*)l,
                                     16, 0, 0);
}

// ---------------- W (E x E) -> W^T bf16 (N-major for GEMM B operand) ----------------
__global__ __launch_bounds__(256) void prep_w(const float* __restrict__ Wq,
                                              const float* __restrict__ Wk,
                                              const float* __restrict__ Wv,
                                              __bf16* __restrict__ Wt) {
    const int z = blockIdx.z;
    const float* W = (z == 0) ? Wq : ((z == 1) ? Wk : Wv);
    __bf16* dst = Wt + (size_t)z * E * E;
    __shared__ __align__(16) float t[64][65];
    const int n0 = blockIdx.x * 64, k0 = blockIdx.y * 64;
    const int r = threadIdx.x >> 2, c4 = threadIdx.x & 3;
#pragma unroll
    for (int j = 0; j < 4; ++j) {
        const float4 vv = *(const float4*)&W[(size_t)(k0 + r) * E + n0 + c4 * 16 + j * 4];
        t[r][c4 * 16 + j * 4 + 0] = vv.x;
        t[r][c4 * 16 + j * 4 + 1] = vv.y;
        t[r][c4 * 16 + j * 4 + 2] = vv.z;
        t[r][c4 * 16 + j * 4 + 3] = vv.w;
    }
    __syncthreads();
    bf16x8 o0, o1;
#pragma unroll
    for (int j = 0; j < 8; ++j) {
        o0[j] = (__bf16)t[c4 * 16 + j][r];
        o1[j] = (__bf16)t[c4 * 16 + 8 + j][r];
    }
    *(bf16x8*)&dst[(size_t)(n0 + r) * E + k0 + c4 * 16] = o0;
    *(bf16x8*)&dst[(size_t)(n0 + r) * E + k0 + c4 * 16 + 8] = o1;
}

// ================= 128x128 GEMM, fused f32->bf16 A-staging, XCD-local A =================
// C_z = (X_z @ W_z^T' + b_z) * alpha_z.  256 threads = 4 waves (2M x 2N).
// A staged from the ORIGINAL f32 inputs: global f32x4 loads -> cvt -> swizzled
// ds_write_b128 (kills the separate 72MB convert pass). B staged via gload_lds
// from bf16 Wt. LDS 80KB dynamic: A dbuf 2x16KB + B TRIPLE-buffer 3x16KB.
// Grid (32,8,3): blockIdx.x = m-panel = XCD selector (linear_id%8 == bx%8), so
// each A panel lives in exactly one XCD's L2, reused by all 8 n-blocks there.
// Per tile T (2 phases):
//   ph0: issue A-f32 loads(T+2)x8 + B gload_lds(T+2)x4 -> slot (T+2)%3;
//        frag-read A(8) + B n0,1(4); BAR; lgkm0; prio1; 16 MFMA; prio0; BAR
//   ph1: vmcnt(4)  [retires B(T+1, oldest) + A(T+2) regs; leaves B(T+2)x4];
//        cvt+ds_write A(T+2) -> A slot T&1 (A(T) reads done at ph0 barrier);
//        frag-read B n2,3; BAR; lgkm0 (drains writes); prio1; 16 MFMA; prio0; BAR
// Ledger: B(T+1) issued at T-1 ph0, older than all tile-T issues -> any
// vmcnt(4) at T ph1 retires it before T+1 ph0 frag reads. A regs protected
// additionally by compiler waits. Tails: T=14 vmcnt(0), T=15 no wait/stage.
__device__ __forceinline__ void stageB(const __bf16* __restrict__ gsrc, int row0, int kcol,
                                       char* ldsdst, int wv, int ln) {
#pragma unroll
    for (int r = 0; r < 4; ++r) {
        const int rowg = row0 + r * 32 + wv * 8 + (ln >> 3);
        const int c16 = (ln & 7) ^ (ln >> 3);   // inverse-swizzled source column
        gload16(gsrc + (size_t)rowg * E + kcol + c16 * 8,
                ldsdst + r * 4096 + wv * 1024);
    }
}

__device__ __forceinline__ void loadA_f32(const float* __restrict__ gsrc, int row0, int kcol,
                                          float4 (&o)[4][2], int wv, int ln) {
#pragma unroll
    for (int r = 0; r < 4; ++r) {
        const int rowg = row0 + r * 32 + wv * 8 + (ln >> 3);
        const int c16 = (ln & 7) ^ (ln >> 3);
        const float* p = gsrc + (size_t)rowg * E + kcol + c16 * 8;
        o[r][0] = *(const float4*)p;
        o[r][1] = *(const float4*)(p + 4);
    }
}

__device__ __forceinline__ void writeA_lds(const float4 (&a)[4][2], char* dst, int wv, int ln) {
#pragma unroll
    for (int r = 0; r < 4; ++r) {
        bf16x8 o;
        o[0] = (__bf16)a[r][0].x; o[1] = (__bf16)a[r][0].y;
        o[2] = (__bf16)a[r][0].z; o[3] = (__bf16)a[r][0].w;
        o[4] = (__bf16)a[r][1].x; o[5] = (__bf16)a[r][1].y;
        o[6] = (__bf16)a[r][1].z; o[7] = (__bf16)a[r][1].w;
        *(bf16x8*)(dst + r * 4096 + wv * 1024 + ln * 16) = o;
    }
}

__device__ __forceinline__ bf16x8 fragld(const char* base, int row, int kk, int kg) {
    return *(const bf16x8*)(base + row * 128 + ((((kk << 2) | kg) ^ (row & 7)) << 4));
}

#define PH_SYNC_BEGIN  __builtin_amdgcn_s_barrier(); \
                       asm volatile("s_waitcnt lgkmcnt(0)" ::: "memory"); \
                       __builtin_amdgcn_sched_barrier(0); \
                       __builtin_amdgcn_s_setprio(1);
#define PH_SYNC_END    __builtin_amdgcn_s_setprio(0); \
                       __builtin_amdgcn_s_barrier();

__global__ __launch_bounds__(256, 2) void gemm_qkv(const float* __restrict__ xq,
                                                   const float* __restrict__ xk,
                                                   const float* __restrict__ xv,
                                                   const __bf16* __restrict__ Wt,
                                                   const float* __restrict__ bq,
                                                   const float* __restrict__ bk,
                                                   const float* __restrict__ bv,
                                                   __bf16* __restrict__ Cb) {
    extern __shared__ __align__(16) char smem[];
    const int z = blockIdx.z;
    const float* A = (z == 0) ? xq : ((z == 1) ? xk : xv);
    const __bf16* B = Wt + (size_t)z * E * E;
    __bf16* C = Cb + (size_t)z * ROWS * E;
    const float* bias = (z == 0) ? bq : ((z == 1) ? bk : bv);
    const float alpha = (z == 0) ? 0.03125f : 1.0f;  // E^-0.5 = 1/32 for Q
    const int m0 = blockIdx.x * 128, n0 = blockIdx.y * 128;   // bx = m = XCD selector
    const int tid = threadIdx.x, ln = tid & 63, wv = tid >> 6;
    const int lr = ln & 15, kg = ln >> 4;
    const int wm = (wv & 1) * 64, wn = (wv >> 1) * 64;

    // prologue: B(0),B(1) via gload_lds; A(0),A(1) via regs
    stageB(B, n0, 0,  smem + 32768, wv, ln);           // B slot 0
    stageB(B, n0, 64, smem + 49152, wv, ln);           // B slot 1
    float4 a0r[4][2], a1r[4][2];
    loadA_f32(A, m0, 0,  a0r, wv, ln);
    loadA_f32(A, m0, 64, a1r, wv, ln);
    asm volatile("s_waitcnt vmcnt(16)" ::: "memory");  // B(0),B(1) retired
    writeA_lds(a0r, smem,        wv, ln);              // compiler waits a0r
    writeA_lds(a1r, smem + 16384, wv, ln);             // compiler waits a1r
    asm volatile("s_waitcnt lgkmcnt(0)" ::: "memory");
    __builtin_amdgcn_s_barrier();

    f32x4 acc[4][4] = {};
    bf16x8 Af[4][2], Bf[2][2];
    float4 areg[4][2];

#define LOAD_B(nb) \
    _Pragma("unroll") for (int nn = 0; nn < 2; ++nn) \
    _Pragma("unroll") for (int kk = 0; kk < 2; ++kk) \
        Bf[nn][kk] = fragld(cB, wn + ((nb) + nn) * 16 + lr, kk, kg);
#define QUAD(q) \
    _Pragma("unroll") for (int m = 0; m < 4; ++m) \
    _Pragma("unroll") for (int nn = 0; nn < 2; ++nn) \
    _Pragma("unroll") for (int kk = 0; kk < 2; ++kk) \
        acc[m][2 * (q) + nn] = __builtin_amdgcn_mfma_f32_16x16x32_bf16(Af[m][kk], Bf[nn][kk], acc[m][2 * (q) + nn], 0, 0, 0);

    for (int T = 0; T < 16; ++T) {
        const char* cA = smem + (T & 1) * 16384;
        const char* cB = smem + 32768 + (T % 3) * 16384;
        char* nA = smem + (T & 1) * 16384;               // A(T+2) replaces A(T)
        char* nB = smem + 32768 + ((T + 2) % 3) * 16384; // B(T+2) -> slot (T+2)%3
        // ---- phase 0 ----
        if (T < 14) {
            loadA_f32(A, m0, (T + 2) * 64, areg, wv, ln);  // 8 vmem (older)
            stageB(B, n0, (T + 2) * 64, nB, wv, ln);       // 4 vmem (newer)
        }
#pragma unroll
        for (int m = 0; m < 4; ++m)
#pragma unroll
            for (int kk = 0; kk < 2; ++kk)
                Af[m][kk] = fragld(cA, wm + m * 16 + lr, kk, kg);
        LOAD_B(0);
        PH_SYNC_BEGIN; QUAD(0); PH_SYNC_END;
        // ---- phase 1 ----
        if (T < 14)       { asm volatile("s_waitcnt vmcnt(4)" ::: "memory"); }
        else if (T == 14) { asm volatile("s_waitcnt vmcnt(0)" ::: "memory"); }
        if (T < 14) writeA_lds(areg, nA, wv, ln);
        LOAD_B(2);
        PH_SYNC_BEGIN; QUAD(1); PH_SYNC_END;
    }
#undef LOAD_B
#undef QUAD

    // epilogue: D row = kg*4+rr (M side), col = lr (N side)
#pragma unroll
    for (int m = 0; m < 4; ++m) {
        const int rbase = m0 + wm + m * 16 + kg * 4;
#pragma unroll
        for (int n = 0; n < 4; ++n) {
            const int col = n0 + wn + n * 16 + lr;
            const float bcol = bias[col];
#pragma unroll
            for (int rr = 0; rr < 4; ++rr)
                C[(size_t)(rbase + rr) * E + col] = (__bf16)((acc[m][n][rr] + bcol) * alpha);
        }
    }
}

// ---------------- per-(batch,head) MFMA reduction over a 128-t slice ----------------
__global__ __launch_bounds__(256) void reduce_kv(const __bf16* __restrict__ Kb,
                                                 const __bf16* __restrict__ Vb,
                                                 float* __restrict__ Mpart,
                                                 float* __restrict__ ksumP,
                                                 float* __restrict__ vsumP) {
    const int bh = blockIdx.x, b = bh >> 4, h = bh & 15;
    const int ts = blockIdx.y;
    const int t0 = ts * 128;
    __shared__ __align__(16) __bf16 sK[128 * 64];   // 16 KiB, swizzled
    __shared__ __align__(16) __bf16 sV[128 * 64];   // 16 KiB, swizzled
    __shared__ float red_k[4][64];
    __shared__ float red_v[4][64];
    const int tid = threadIdx.x;
    const int lane = tid & 63, wave = tid >> 6;
    const int lr = lane & 15, kg = lane >> 4;

    float vk[8] = {}, vv[8] = {};
    const int d0 = (tid & 7) * 8;
#pragma unroll
    for (int i = 0; i < 4; ++i) {
        const int t = i * 32 + (tid >> 3);
        const size_t g = (size_t)((t0 + t) * 2 + b) * E + h * 64 + d0;
        const bf16x8 kv = *(const bf16x8*)&Kb[g];
        const bf16x8 vvv = *(const bf16x8*)&Vb[g];
        const int lo = (t * 128 + d0 * 2) ^ (wave << 5);
        *(bf16x8*)((char*)sK + lo) = kv;
        *(bf16x8*)((char*)sV + lo) = vvv;
#pragma unroll
        for (int j = 0; j < 8; ++j) { vk[j] += (float)kv[j]; vv[j] += (float)vvv[j]; }
    }
#pragma unroll
    for (int m = 8; m <= 32; m <<= 1)
#pragma unroll
        for (int j = 0; j < 8; ++j) {
            vk[j] += __shfl_xor(vk[j], m, 64);
            vv[j] += __shfl_xor(vv[j], m, 64);
        }
    if (lane < 8)
#pragma unroll
        for (int j = 0; j < 8; ++j) {
            red_k[wave][lane * 8 + j] = vk[j];
            red_v[wave][lane * 8 + j] = vv[j];
        }
    __syncthreads();

    f32x4 acc[4] = {};
#pragma unroll
    for (int kt = 0; kt < 4; ++kt) {
        const int tb = kt * 32;
        bf16x8 afr, bfr[4];
        const char* pv = (const char*)sV + (((tb + kg * 8) * 128 + (wave * 16 + lr) * 2) ^ (kg << 5));
#pragma unroll
        for (int j = 0; j < 8; ++j) afr[j] = *(const __bf16*)(pv + j * 128);
#pragma unroll
        for (int ni = 0; ni < 4; ++ni) {
            const char* pk = (const char*)sK + (((tb + kg * 8) * 128 + (ni * 16 + lr) * 2) ^ (kg << 5));
#pragma unroll
            for (int j = 0; j < 8; ++j) bfr[ni][j] = *(const __bf16*)(pk + j * 128);
        }
#pragma unroll
        for (int ni = 0; ni < 4; ++ni)
            acc[ni] = __builtin_amdgcn_mfma_f32_16x16x32_bf16(afr, bfr[ni], acc[ni], 0, 0, 0);
    }

    float* Mp = Mpart + ((size_t)bh * 16 + ts) * 4096;
#pragma unroll
    for (int ni = 0; ni < 4; ++ni)
#pragma unroll
        for (int rr = 0; rr < 4; ++rr)
            Mp[(wave * 16 + kg * 4 + rr) * 64 + ni * 16 + lr] = acc[ni][rr];
    if (tid < 64)
        ksumP[(bh * 16 + ts) * 64 + tid] = red_k[0][tid] + red_k[1][tid] + red_k[2][tid] + red_k[3][tid];
    else if (tid < 128) {
        const int d = tid - 64;
        vsumP[(bh * 16 + ts) * 64 + d] = red_v[0][d] + red_v[1][d] + red_v[2][d] + red_v[3][d];
    }
}

// ---------------- combine the 16 t-split partials ----------------
__global__ __launch_bounds__(256) void combine_m(const float* __restrict__ Mpart,
                                                 const float* __restrict__ ksumP,
                                                 const float* __restrict__ vsumP,
                                                 float* __restrict__ Mt,
                                                 float* __restrict__ ksum,
                                                 float* __restrict__ vsum) {
    const int blk = blockIdx.x, tid = threadIdx.x;
    if (blk < 256) {
        const int e2 = (blk * 256 + tid) * 2;          // 131072 Mt elements, 2/thread
        const int bh = e2 >> 12, r = e2 & 4095;
        const float* src = Mpart + (size_t)bh * 16 * 4096 + r;
        float s0 = 0.f, s1 = 0.f;
#pragma unroll
        for (int ts = 0; ts < 16; ++ts) {
            s0 += src[ts * 4096];
            s1 += src[ts * 4096 + 1];
        }
        Mt[(size_t)bh * 4096 + r] = s0;
        Mt[(size_t)bh * 4096 + r + 1] = s1;
    } else if (blk < 264) {
        const int idx = (blk - 256) * 256 + tid;       // 2048 ksum elements
        const int bh = idx >> 6, d = idx & 63;
        float s = 0.f;
#pragma unroll
        for (int ts = 0; ts < 16; ++ts) s += ksumP[bh * 1024 + ts * 64 + d];
        ksum[idx] = s;
    } else {
        const int idx = (blk - 264) * 256 + tid;       // 2048 vsum elements
        const int bh = idx >> 6, d = idx & 63;
        float s = 0.f;
#pragma unroll
        for (int ts = 0; ts < 16; ++ts) s += vsumP[bh * 1024 + ts * 64 + d];
        vsum[idx] = s;
    }
}

// ---------------- epilogue: out[r, h*64+d2] = (v_sum[d2] + sum_d1 Q[r,d1]*M[d1][d2]) / Z_r ----
__global__ __launch_bounds__(256) void taylor_out(const __bf16* __restrict__ Qb,
                                                  const float* __restrict__ Mt,
                                                  const float* __restrict__ ksum,
                                                  const float* __restrict__ vsum,
                                                  float* __restrict__ out) {
    const int b = blockIdx.y;
    const int lblk = blockIdx.x * 16;
    const int tid = threadIdx.x, lane = tid & 63, wave = tid >> 6;
    const int lr = lane & 15, kg = lane >> 4;
    __shared__ __align__(16) __bf16 sM[4][4096];  // 4 heads' Mt (bf16, swizzled), 32 KiB
    for (int hh = 0; hh < 4; ++hh) {
        __syncthreads();
#pragma unroll
        for (int i = 0; i < 8; ++i) {
            const int idx = i * 256 + tid;  // 0..2047 chunks of 8 floats
            const int hseg = idx >> 9, rem = idx & 511;
            const float* src = &Mt[(size_t)(b * 16 + hseg * 4 + hh) * 4096 + rem * 8];
            const float4 mA = *(const float4*)src;
            const float4 mB = *(const float4*)(src + 4);
            bf16x8 o;
            o[0] = (__bf16)mA.x; o[1] = (__bf16)mA.y; o[2] = (__bf16)mA.z; o[3] = (__bf16)mA.w;
            o[4] = (__bf16)mB.x; o[5] = (__bf16)mB.y; o[6] = (__bf16)mB.z; o[7] = (__bf16)mB.w;
            *(bf16x8*)((char*)&sM[hseg][0] + SWZ(rem * 16)) = o;
        }
        __syncthreads();
        const int h = wave * 4 + hh;
        const int bh = b * 16 + h;
        const int rA = (lblk + lr) * 2 + b;
        const bf16x8 a0 = *(const bf16x8*)&Qb[(size_t)rA * E + h * 64 + kg * 8];
        const bf16x8 a1 = *(const bf16x8*)&Qb[(size_t)rA * E + h * 64 + 32 + kg * 8];
        float p = 0.f;
        const float* ks = &ksum[bh * 64];
#pragma unroll
        for (int j = 0; j < 8; ++j)
            p += (float)a0[j] * ks[kg * 8 + j] + (float)a1[j] * ks[32 + kg * 8 + j];
        p += __shfl_xor(p, 16, 64);
        p += __shfl_xor(p, 32, 64);
        const float Z = 2048.0f + p;
        f32x4 acc[4] = {};
#pragma unroll
        for (int ni = 0; ni < 4; ++ni) {
            const int byt0 = (ni * 16 + lr) * 128 + kg * 16;
            const bf16x8 b0 = *(const bf16x8*)((const char*)&sM[wave][0] + SWZ(byt0));
            const bf16x8 b1 = *(const bf16x8*)((const char*)&sM[wave][0] + SWZ(byt0 + 64));
            acc[ni] = __builtin_amdgcn_mfma_f32_16x16x32_bf16(a0, b0, acc[ni], 0, 0, 0);
            acc[ni] = __builtin_amdgcn_mfma_f32_16x16x32_bf16(a1, b1, acc[ni], 0, 0, 0);
        }
        float invZ[4];
#pragma unroll
        for (int rr = 0; rr < 4; ++rr) invZ[rr] = 1.0f / __shfl(Z, kg * 4 + rr, 64);
        const float* vs = &vsum[bh * 64];
#pragma unroll
        for (int ni = 0; ni < 4; ++ni)
#pragma unroll
            for (int rr = 0; rr < 4; ++rr) {
                const int l_out = lblk + kg * 4 + rr;
                out[(size_t)(l_out * 2 + b) * E + h * 64 + ni * 16 + lr] =
                    (vs[ni * 16 + lr] + acc[ni][rr]) * invZ[rr];
            }
    }
}

extern "C" void kernel_launch(void* const* d_in, const int* in_sizes, int n_in,
                              void* d_out, int out_size, void* d_ws, size_t ws_size,
                              hipStream_t stream) {
    const float* q  = (const float*)d_in[0];
    const float* k  = (const float*)d_in[1];
    const float* v  = (const float*)d_in[2];
    const float* Wq = (const float*)d_in[3];
    const float* bq = (const float*)d_in[4];
    const float* Wk = (const float*)d_in[5];
    const float* bk = (const float*)d_in[6];
    const float* Wv = (const float*)d_in[7];
    const float* bv = (const float*)d_in[8];
    float* out = (float*)d_out;
    char* w = (char*)d_ws;
    // workspace layout (~40.6 MB)
    __bf16* Wt = (__bf16*)(w);               // 3 x 1024x1024 bf16 ( 6 MiB)
    __bf16* Cb = (__bf16*)(w + 6291456);     // Q,K,V bf16         (24 MiB)
    float* Mt    = (float*)(w + 31457280);   // 32 x 64 x 64 f32 (Mt[d2][d1])
    float* ksum  = (float*)(w + 31981568);   // 32 x 64
    float* vsum  = (float*)(w + 31989760);   // 32 x 64
    float* Mpart = (float*)(w + 31997952);   // 32 x 16 x 4096 f32 (8 MiB)
    float* ksumP = (float*)(w + 40386560);   // 32 x 16 x 64 f32
    float* vsumP = (float*)(w + 40517632);   // 32 x 16 x 64 f32

    hipFuncSetAttribute((const void*)gemm_qkv,
                        hipFuncAttributeMaxDynamicSharedMemorySize, 81920);
    prep_w<<<dim3(16, 16, 3), 256, 0, stream>>>(Wq, Wk, Wv, Wt);
    gemm_qkv<<<dim3(32, 8, 3), 256, 81920, stream>>>(q, k, v, Wt, bq, bk, bv, Cb);
    reduce_kv<<<dim3(32, 16), 256, 0, stream>>>(Cb + (size_t)ROWS * E,
                                                Cb + 2 * (size_t)ROWS * E, Mpart, ksumP, vsumP);
    combine_m<<<272, 256, 0, stream>>>(Mpart, ksumP, vsumP, Mt, ksum, vsum);
    taylor_out<<<dim3(128, 2), 256, 0, stream>>>(Cb, Mt, ksum, vsum, out);
}

// Round 9
// 74.442 us; speedup vs baseline: 1.1850x; 1.1850x over previous
//
#include <hip/hip_runtime.h>
#include <hip/hip_bf16.h>

// Problem constants
#define L_SEQ 2048
#define BATCH 2
#define ROWS 4096          // L*B, row index = l*2 + b
#define E 1024
#define NH 16
#define HD 64

typedef __attribute__((ext_vector_type(4))) float f32x4;
typedef __attribute__((ext_vector_type(8))) __bf16 bf16x8;

// XOR swizzle for 128-byte-row LDS tiles (break same-bank column reads)
#define SWZ(byt) ((byt) ^ ((((byt) >> 7) & 7) << 4))

__device__ __forceinline__ void gload16(const void* g, void* l) {
    __builtin_amdgcn_global_load_lds((const __attribute__((address_space(1))) void*)g,
                                     (__attribute__((address_space(3))) void*)l,
                                     16, 0, 0);
}

// ---------------- W (E x E) -> W^T bf16 (N-major for GEMM B operand) ----------------
__global__ __launch_bounds__(256) void prep_w(const float* __restrict__ Wq,
                                              const float* __restrict__ Wk,
                                              const float* __restrict__ Wv,
                                              __bf16* __restrict__ Wt) {
    const int z = blockIdx.z;
    const float* W = (z == 0) ? Wq : ((z == 1) ? Wk : Wv);
    __bf16* dst = Wt + (size_t)z * E * E;
    __shared__ __align__(16) float t[64][65];
    const int n0 = blockIdx.x * 64, k0 = blockIdx.y * 64;
    const int r = threadIdx.x >> 2, c4 = threadIdx.x & 3;
#pragma unroll
    for (int j = 0; j < 4; ++j) {
        const float4 vv = *(const float4*)&W[(size_t)(k0 + r) * E + n0 + c4 * 16 + j * 4];
        t[r][c4 * 16 + j * 4 + 0] = vv.x;
        t[r][c4 * 16 + j * 4 + 1] = vv.y;
        t[r][c4 * 16 + j * 4 + 2] = vv.z;
        t[r][c4 * 16 + j * 4 + 3] = vv.w;
    }
    __syncthreads();
    bf16x8 o0, o1;
#pragma unroll
    for (int j = 0; j < 8; ++j) {
        o0[j] = (__bf16)t[c4 * 16 + j][r];
        o1[j] = (__bf16)t[c4 * 16 + 8 + j][r];
    }
    *(bf16x8*)&dst[(size_t)(n0 + r) * E + k0 + c4 * 16] = o0;
    *(bf16x8*)&dst[(size_t)(n0 + r) * E + k0 + c4 * 16 + 8] = o1;
}

// ===== 128x128 GEMM, fused f32->bf16 A-staging (2-deep reg pipeline), XCD-local A =====
// R8 post-mortem: 1-deep areg forced a per-tile latency stall (issue at ph0,
// retire at ph1 of the SAME tile). Fix: two named reg buffers, issue A(T+3) at
// tile-T ph0, LDS-write A(T+2) (loaded at T-1 ph0) at tile-T ph1 -> 3-phase depth.
// vmcnt ledger (issue order per tile T ph0: A(T+3)x8 then B(T+2)x4 = 12/tile):
//   at T ph1 outstanding = {A(T+2),B(T+1)} + {A(T+3),B(T+2)} = 24;
//   vmcnt(12) retires A(T+2) (for the reg->LDS write) and B(T+1) (read next
//   tile, published by this phase's closing barrier). Tails: T=13 issues no A
//   (outstanding 16) -> vmcnt(4); T=14 -> vmcnt(0); T=15 none.
// A slot for T+2 = slot T&1 (A(T) frag reads completed at T ph0 barrier).
// B slots %3 (staged 4 phases ahead). Grid (32,8,3): blockIdx.x = m-panel =
// XCD selector -> each A f32 panel is fetched by exactly one XCD's L2.
__device__ __forceinline__ void stageB(const __bf16* __restrict__ gsrc, int row0, int kcol,
                                       char* ldsdst, int wv, int ln) {
#pragma unroll
    for (int r = 0; r < 4; ++r) {
        const int rowg = row0 + r * 32 + wv * 8 + (ln >> 3);
        const int c16 = (ln & 7) ^ (ln >> 3);   // inverse-swizzled source column
        gload16(gsrc + (size_t)rowg * E + kcol + c16 * 8,
                ldsdst + r * 4096 + wv * 1024);
    }
}

__device__ __forceinline__ void loadA_f32(const float* __restrict__ gsrc, int row0, int kcol,
                                          float4 (&o)[4][2], int wv, int ln) {
#pragma unroll
    for (int r = 0; r < 4; ++r) {
        const int rowg = row0 + r * 32 + wv * 8 + (ln >> 3);
        const int c16 = (ln & 7) ^ (ln >> 3);
        const float* p = gsrc + (size_t)rowg * E + kcol + c16 * 8;
        o[r][0] = *(const float4*)p;
        o[r][1] = *(const float4*)(p + 4);
    }
}

__device__ __forceinline__ void writeA_lds(const float4 (&a)[4][2], char* dst, int wv, int ln) {
#pragma unroll
    for (int r = 0; r < 4; ++r) {
        bf16x8 o;
        o[0] = (__bf16)a[r][0].x; o[1] = (__bf16)a[r][0].y;
        o[2] = (__bf16)a[r][0].z; o[3] = (__bf16)a[r][0].w;
        o[4] = (__bf16)a[r][1].x; o[5] = (__bf16)a[r][1].y;
        o[6] = (__bf16)a[r][1].z; o[7] = (__bf16)a[r][1].w;
        *(bf16x8*)(dst + r * 4096 + wv * 1024 + ln * 16) = o;
    }
}

__device__ __forceinline__ bf16x8 fragld(const char* base, int row, int kk, int kg) {
    return *(const bf16x8*)(base + row * 128 + ((((kk << 2) | kg) ^ (row & 7)) << 4));
}

#define PH_SYNC_BEGIN  __builtin_amdgcn_s_barrier(); \
                       asm volatile("s_waitcnt lgkmcnt(0)" ::: "memory"); \
                       __builtin_amdgcn_sched_barrier(0); \
                       __builtin_amdgcn_s_setprio(1);
#define PH_SYNC_END    __builtin_amdgcn_s_setprio(0); \
                       __builtin_amdgcn_s_barrier();

__global__ __launch_bounds__(256, 2) void gemm_qkv(const float* __restrict__ xq,
                                                   const float* __restrict__ xk,
                                                   const float* __restrict__ xv,
                                                   const __bf16* __restrict__ Wt,
                                                   const float* __restrict__ bq,
                                                   const float* __restrict__ bk,
                                                   const float* __restrict__ bv,
                                                   __bf16* __restrict__ Cb) {
    extern __shared__ __align__(16) char smem[];
    const int z = blockIdx.z;
    const float* A = (z == 0) ? xq : ((z == 1) ? xk : xv);
    const __bf16* B = Wt + (size_t)z * E * E;
    __bf16* C = Cb + (size_t)z * ROWS * E;
    const float* bias = (z == 0) ? bq : ((z == 1) ? bk : bv);
    const float alpha = (z == 0) ? 0.03125f : 1.0f;  // E^-0.5 = 1/32 for Q
    const int m0 = blockIdx.x * 128, n0 = blockIdx.y * 128;   // bx = m = XCD selector
    const int tid = threadIdx.x, ln = tid & 63, wv = tid >> 6;
    const int lr = ln & 15, kg = ln >> 4;
    const int wm = (wv & 1) * 64, wn = (wv >> 1) * 64;

    float4 aregA[4][2], aregB[4][2];   // named 2-deep A pipeline (rule #20: no runtime idx)

    // prologue: B(0),B(1) -> LDS; A(0),A(1) -> regs -> LDS; then issue A(2)->aregA
    stageB(B, n0, 0,  smem + 32768, wv, ln);           // B slot 0
    stageB(B, n0, 64, smem + 49152, wv, ln);           // B slot 1
    loadA_f32(A, m0, 0,  aregA, wv, ln);
    loadA_f32(A, m0, 64, aregB, wv, ln);
    asm volatile("s_waitcnt vmcnt(0)" ::: "memory");
    writeA_lds(aregA, smem,        wv, ln);
    writeA_lds(aregB, smem + 16384, wv, ln);
    loadA_f32(A, m0, 128, aregA, wv, ln);              // A(2), written at T=0 ph1
    asm volatile("s_waitcnt lgkmcnt(0)" ::: "memory");
    __builtin_amdgcn_s_barrier();

    f32x4 acc[4][4] = {};
    bf16x8 Af[4][2], Bf[2][2];

#define LOAD_B(nb) \
    _Pragma("unroll") for (int nn = 0; nn < 2; ++nn) \
    _Pragma("unroll") for (int kk = 0; kk < 2; ++kk) \
        Bf[nn][kk] = fragld(cB, wn + ((nb) + nn) * 16 + lr, kk, kg);
#define QUAD(q) \
    _Pragma("unroll") for (int m = 0; m < 4; ++m) \
    _Pragma("unroll") for (int nn = 0; nn < 2; ++nn) \
    _Pragma("unroll") for (int kk = 0; kk < 2; ++kk) \
        acc[m][2 * (q) + nn] = __builtin_amdgcn_mfma_f32_16x16x32_bf16(Af[m][kk], Bf[nn][kk], acc[m][2 * (q) + nn], 0, 0, 0);

// One tile body. ALOAD = areg[(T+3)&1] (gets A(T+3)); AWRITE = areg[(T+2)&1] = areg[T&1].
#define GBODY(TT, ALOAD, AWRITE)                                                  \
    {                                                                             \
        const int Tv = (TT);                                                      \
        const char* cA = smem + (Tv & 1) * 16384;                                 \
        const char* cB = smem + 32768 + (Tv % 3) * 16384;                         \
        char* nA = smem + (Tv & 1) * 16384;                                       \
        char* nB = smem + 32768 + ((Tv + 2) % 3) * 16384;                         \
        /* ---- phase 0 ---- */                                                   \
        if (Tv <= 12) loadA_f32(A, m0, (Tv + 3) * 64, ALOAD, wv, ln);             \
        if (Tv <= 13) stageB(B, n0, (Tv + 2) * 64, nB, wv, ln);                   \
        _Pragma("unroll") for (int m = 0; m < 4; ++m)                             \
        _Pragma("unroll") for (int kk = 0; kk < 2; ++kk)                          \
            Af[m][kk] = fragld(cA, wm + m * 16 + lr, kk, kg);                     \
        LOAD_B(0);                                                                \
        PH_SYNC_BEGIN; QUAD(0); PH_SYNC_END;                                      \
        /* ---- phase 1 ---- */                                                   \
        if (Tv <= 12)      { asm volatile("s_waitcnt vmcnt(12)" ::: "memory"); }  \
        else if (Tv == 13) { asm volatile("s_waitcnt vmcnt(4)"  ::: "memory"); }  \
        else if (Tv == 14) { asm volatile("s_waitcnt vmcnt(0)"  ::: "memory"); }  \
        if (Tv <= 13) writeA_lds(AWRITE, nA, wv, ln);                             \
        LOAD_B(2);                                                                \
        PH_SYNC_BEGIN; QUAD(1); PH_SYNC_END;                                      \
    }

    for (int t = 0; t < 8; ++t) {
        GBODY(2 * t,     aregB, aregA);   // even T: A(T+3)->aregB, write aregA
        GBODY(2 * t + 1, aregA, aregB);   // odd  T: A(T+3)->aregA, write aregB
    }
#undef GBODY
#undef LOAD_B
#undef QUAD

    // epilogue: D row = kg*4+rr (M side), col = lr (N side)
#pragma unroll
    for (int m = 0; m < 4; ++m) {
        const int rbase = m0 + wm + m * 16 + kg * 4;
#pragma unroll
        for (int n = 0; n < 4; ++n) {
            const int col = n0 + wn + n * 16 + lr;
            const float bcol = bias[col];
#pragma unroll
            for (int rr = 0; rr < 4; ++rr)
                C[(size_t)(rbase + rr) * E + col] = (__bf16)((acc[m][n][rr] + bcol) * alpha);
        }
    }
}

// ---------------- per-(batch,head) MFMA reduction over a 128-t slice ----------------
__global__ __launch_bounds__(256) void reduce_kv(const __bf16* __restrict__ Kb,
                                                 const __bf16* __restrict__ Vb,
                                                 float* __restrict__ Mpart,
                                                 float* __restrict__ ksumP,
                                                 float* __restrict__ vsumP) {
    const int bh = blockIdx.x, b = bh >> 4, h = bh & 15;
    const int ts = blockIdx.y;
    const int t0 = ts * 128;
    __shared__ __align__(16) __bf16 sK[128 * 64];   // 16 KiB, swizzled
    __shared__ __align__(16) __bf16 sV[128 * 64];   // 16 KiB, swizzled
    __shared__ float red_k[4][64];
    __shared__ float red_v[4][64];
    const int tid = threadIdx.x;
    const int lane = tid & 63, wave = tid >> 6;
    const int lr = lane & 15, kg = lane >> 4;

    float vk[8] = {}, vv[8] = {};
    const int d0 = (tid & 7) * 8;
#pragma unroll
    for (int i = 0; i < 4; ++i) {
        const int t = i * 32 + (tid >> 3);
        const size_t g = (size_t)((t0 + t) * 2 + b) * E + h * 64 + d0;
        const bf16x8 kv = *(const bf16x8*)&Kb[g];
        const bf16x8 vvv = *(const bf16x8*)&Vb[g];
        const int lo = (t * 128 + d0 * 2) ^ (wave << 5);
        *(bf16x8*)((char*)sK + lo) = kv;
        *(bf16x8*)((char*)sV + lo) = vvv;
#pragma unroll
        for (int j = 0; j < 8; ++j) { vk[j] += (float)kv[j]; vv[j] += (float)vvv[j]; }
    }
#pragma unroll
    for (int m = 8; m <= 32; m <<= 1)
#pragma unroll
        for (int j = 0; j < 8; ++j) {
            vk[j] += __shfl_xor(vk[j], m, 64);
            vv[j] += __shfl_xor(vv[j], m, 64);
        }
    if (lane < 8)
#pragma unroll
        for (int j = 0; j < 8; ++j) {
            red_k[wave][lane * 8 + j] = vk[j];
            red_v[wave][lane * 8 + j] = vv[j];
        }
    __syncthreads();

    f32x4 acc[4] = {};
#pragma unroll
    for (int kt = 0; kt < 4; ++kt) {
        const int tb = kt * 32;
        bf16x8 afr, bfr[4];
        const char* pv = (const char*)sV + (((tb + kg * 8) * 128 + (wave * 16 + lr) * 2) ^ (kg << 5));
#pragma unroll
        for (int j = 0; j < 8; ++j) afr[j] = *(const __bf16*)(pv + j * 128);
#pragma unroll
        for (int ni = 0; ni < 4; ++ni) {
            const char* pk = (const char*)sK + (((tb + kg * 8) * 128 + (ni * 16 + lr) * 2) ^ (kg << 5));
#pragma unroll
            for (int j = 0; j < 8; ++j) bfr[ni][j] = *(const __bf16*)(pk + j * 128);
        }
#pragma unroll
        for (int ni = 0; ni < 4; ++ni)
            acc[ni] = __builtin_amdgcn_mfma_f32_16x16x32_bf16(afr, bfr[ni], acc[ni], 0, 0, 0);
    }

    float* Mp = Mpart + ((size_t)bh * 16 + ts) * 4096;
#pragma unroll
    for (int ni = 0; ni < 4; ++ni)
#pragma unroll
        for (int rr = 0; rr < 4; ++rr)
            Mp[(wave * 16 + kg * 4 + rr) * 64 + ni * 16 + lr] = acc[ni][rr];
    if (tid < 64)
        ksumP[(bh * 16 + ts) * 64 + tid] = red_k[0][tid] + red_k[1][tid] + red_k[2][tid] + red_k[3][tid];
    else if (tid < 128) {
        const int d = tid - 64;
        vsumP[(bh * 16 + ts) * 64 + d] = red_v[0][d] + red_v[1][d] + red_v[2][d] + red_v[3][d];
    }
}

// ---------------- combine the 16 t-split partials ----------------
__global__ __launch_bounds__(256) void combine_m(const float* __restrict__ Mpart,
                                                 const float* __restrict__ ksumP,
                                                 const float* __restrict__ vsumP,
                                                 float* __restrict__ Mt,
                                                 float* __restrict__ ksum,
                                                 float* __restrict__ vsum) {
    const int blk = blockIdx.x, tid = threadIdx.x;
    if (blk < 256) {
        const int e2 = (blk * 256 + tid) * 2;          // 131072 Mt elements, 2/thread
        const int bh = e2 >> 12, r = e2 & 4095;
        const float* src = Mpart + (size_t)bh * 16 * 4096 + r;
        float s0 = 0.f, s1 = 0.f;
#pragma unroll
        for (int ts = 0; ts < 16; ++ts) {
            s0 += src[ts * 4096];
            s1 += src[ts * 4096 + 1];
        }
        Mt[(size_t)bh * 4096 + r] = s0;
        Mt[(size_t)bh * 4096 + r + 1] = s1;
    } else if (blk < 264) {
        const int idx = (blk - 256) * 256 + tid;       // 2048 ksum elements
        const int bh = idx >> 6, d = idx & 63;
        float s = 0.f;
#pragma unroll
        for (int ts = 0; ts < 16; ++ts) s += ksumP[bh * 1024 + ts * 64 + d];
        ksum[idx] = s;
    } else {
        const int idx = (blk - 264) * 256 + tid;       // 2048 vsum elements
        const int bh = idx >> 6, d = idx & 63;
        float s = 0.f;
#pragma unroll
        for (int ts = 0; ts < 16; ++ts) s += vsumP[bh * 1024 + ts * 64 + d];
        vsum[idx] = s;
    }
}

// ---------------- epilogue: out[r, h*64+d2] = (v_sum[d2] + sum_d1 Q[r,d1]*M[d1][d2]) / Z_r ----
__global__ __launch_bounds__(256) void taylor_out(const __bf16* __restrict__ Qb,
                                                  const float* __restrict__ Mt,
                                                  const float* __restrict__ ksum,
                                                  const float* __restrict__ vsum,
                                                  float* __restrict__ out) {
    const int b = blockIdx.y;
    const int lblk = blockIdx.x * 16;
    const int tid = threadIdx.x, lane = tid & 63, wave = tid >> 6;
    const int lr = lane & 15, kg = lane >> 4;
    __shared__ __align__(16) __bf16 sM[4][4096];  // 4 heads' Mt (bf16, swizzled), 32 KiB
    for (int hh = 0; hh < 4; ++hh) {
        __syncthreads();
#pragma unroll
        for (int i = 0; i < 8; ++i) {
            const int idx = i * 256 + tid;  // 0..2047 chunks of 8 floats
            const int hseg = idx >> 9, rem = idx & 511;
            const float* src = &Mt[(size_t)(b * 16 + hseg * 4 + hh) * 4096 + rem * 8];
            const float4 mA = *(const float4*)src;
            const float4 mB = *(const float4*)(src + 4);
            bf16x8 o;
            o[0] = (__bf16)mA.x; o[1] = (__bf16)mA.y; o[2] = (__bf16)mA.z; o[3] = (__bf16)mA.w;
            o[4] = (__bf16)mB.x; o[5] = (__bf16)mB.y; o[6] = (__bf16)mB.z; o[7] = (__bf16)mB.w;
            *(bf16x8*)((char*)&sM[hseg][0] + SWZ(rem * 16)) = o;
        }
        __syncthreads();
        const int h = wave * 4 + hh;
        const int bh = b * 16 + h;
        const int rA = (lblk + lr) * 2 + b;
        const bf16x8 a0 = *(const bf16x8*)&Qb[(size_t)rA * E + h * 64 + kg * 8];
        const bf16x8 a1 = *(const bf16x8*)&Qb[(size_t)rA * E + h * 64 + 32 + kg * 8];
        float p = 0.f;
        const float* ks = &ksum[bh * 64];
#pragma unroll
        for (int j = 0; j < 8; ++j)
            p += (float)a0[j] * ks[kg * 8 + j] + (float)a1[j] * ks[32 + kg * 8 + j];
        p += __shfl_xor(p, 16, 64);
        p += __shfl_xor(p, 32, 64);
        const float Z = 2048.0f + p;
        f32x4 acc[4] = {};
#pragma unroll
        for (int ni = 0; ni < 4; ++ni) {
            const int byt0 = (ni * 16 + lr) * 128 + kg * 16;
            const bf16x8 b0 = *(const bf16x8*)((const char*)&sM[wave][0] + SWZ(byt0));
            const bf16x8 b1 = *(const bf16x8*)((const char*)&sM[wave][0] + SWZ(byt0 + 64));
            acc[ni] = __builtin_amdgcn_mfma_f32_16x16x32_bf16(a0, b0, acc[ni], 0, 0, 0);
            acc[ni] = __builtin_amdgcn_mfma_f32_16x16x32_bf16(a1, b1, acc[ni], 0, 0, 0);
        }
        float invZ[4];
#pragma unroll
        for (int rr = 0; rr < 4; ++rr) invZ[rr] = 1.0f / __shfl(Z, kg * 4 + rr, 64);
        const float* vs = &vsum[bh * 64];
#pragma unroll
        for (int ni = 0; ni < 4; ++ni)
#pragma unroll
            for (int rr = 0; rr < 4; ++rr) {
                const int l_out = lblk + kg * 4 + rr;
                out[(size_t)(l_out * 2 + b) * E + h * 64 + ni * 16 + lr] =
                    (vs[ni * 16 + lr] + acc[ni][rr]) * invZ[rr];
            }
    }
}

extern "C" void kernel_launch(void* const* d_in, const int* in_sizes, int n_in,
                              void* d_out, int out_size, void* d_ws, size_t ws_size,
                              hipStream_t stream) {
    const float* q  = (const float*)d_in[0];
    const float* k  = (const float*)d_in[1];
    const float* v  = (const float*)d_in[2];
    const float* Wq = (const float*)d_in[3];
    const float* bq = (const float*)d_in[4];
    const float* Wk = (const float*)d_in[5];
    const float* bk = (const float*)d_in[6];
    const float* Wv = (const float*)d_in[7];
    const float* bv = (const float*)d_in[8];
    float* out = (float*)d_out;
    char* w = (char*)d_ws;
    // workspace layout (~40.6 MB)
    __bf16* Wt = (__bf16*)(w);               // 3 x 1024x1024 bf16 ( 6 MiB)
    __bf16* Cb = (__bf16*)(w + 6291456);     // Q,K,V bf16         (24 MiB)
    float* Mt    = (float*)(w + 31457280);   // 32 x 64 x 64 f32 (Mt[d2][d1])
    float* ksum  = (float*)(w + 31981568);   // 32 x 64
    float* vsum  = (float*)(w + 31989760);   // 32 x 64
    float* Mpart = (float*)(w + 31997952);   // 32 x 16 x 4096 f32 (8 MiB)
    float* ksumP = (float*)(w + 40386560);   // 32 x 16 x 64 f32
    float* vsumP = (float*)(w + 40517632);   // 32 x 16 x 64 f32

    hipFuncSetAttribute((const void*)gemm_qkv,
                        hipFuncAttributeMaxDynamicSharedMemorySize, 81920);
    prep_w<<<dim3(16, 16, 3), 256, 0, stream>>>(Wq, Wk, Wv, Wt);
    gemm_qkv<<<dim3(32, 8, 3), 256, 81920, stream>>>(q, k, v, Wt, bq, bk, bv, Cb);
    reduce_kv<<<dim3(32, 16), 256, 0, stream>>>(Cb + (size_t)ROWS * E,
                                                Cb + 2 * (size_t)ROWS * E, Mpart, ksumP, vsumP);
    combine_m<<<272, 256, 0, stream>>>(Mpart, ksumP, vsumP, Mt, ksum, vsum);
    taylor_out<<<dim3(128, 2), 256, 0, stream>>>(Cb, Mt, ksum, vsum, out);
}